// Round 3
// baseline (32586.710 us; speedup 1.0000x reference)
//
#include <hip/hip_runtime.h>
#include <cmath>

// Problem constants
constexpr int cS = 256;   // sequence length
constexpr int cB = 32;    // batch
constexpr int cE = 256;   // embedding dim
constexpr int cH = 512;   // hidden
constexpr int cT = 10;    // tags
constexpr float cNEG = -10000.0f;

// ws layout in floats:
//  x      [S][B][E]      = 2,097,152
//  h_all  [S][B][2H]     = 8,388,608   (cols 0:512 fwd, 512:1024 bwd)
//  c_st   [2][B][H]      = 32,768      (zeroed each launch)
//  sync   [2][S] (int)   = 512         (zeroed each launch)
//  feats  [S][B][T]      = 81,920
constexpr size_t X_OFF     = 0;
constexpr size_t HALL_OFF  = X_OFF + (size_t)cS*cB*cE;
constexpr size_t C_OFF     = HALL_OFF + (size_t)cS*cB*2*cH;
constexpr size_t SYNC_OFF  = C_OFF + (size_t)2*cB*cH;
constexpr size_t FEATS_OFF = SYNC_OFF + 512;

__device__ __forceinline__ float sigf(float v) { return 1.0f / (1.0f + expf(-v)); }

// ---------------------------------------------------------------------------
// K1: gather x[s][b][e] = emb[tokens[b][s]][e], float4-vectorized
// ---------------------------------------------------------------------------
__global__ void k_gather(const int* __restrict__ tokens,
                         const float* __restrict__ emb,
                         float* __restrict__ x)
{
    const int idx = blockIdx.x * 512 + threadIdx.x;      // total S*B*E/4 = 524288
    if (idx >= cS * cB * (cE / 4)) return;
    const int s   = idx >> 11;          // / (32*64)
    const int rem = idx & 2047;
    const int b   = rem >> 6;
    const int e4  = rem & 63;
    const int tok = tokens[b * cS + s];
    ((float4*)x)[((size_t)s * cB + b) * 64 + e4] =
        ((const float4*)emb)[(size_t)tok * 64 + e4];
}

// ---------------------------------------------------------------------------
// K2: persistent bidirectional LSTM recurrence.
// 512 blocks: blk>>8 = dir (0 fwd, 1 bwd), blk&255 = unit-pair id.
// Each block: 2 hidden units -> 8 gate rows, for all 32 batch elems.
// Per-step device sync (per direction) via agent-scope counter.
// h handoff via h_all rows (step s writes row t_s, reads row t_{s+-1}).
// ---------------------------------------------------------------------------
__global__ __launch_bounds__(256, 2) void k_recur(
    const float* __restrict__ x,
    float* __restrict__ h_all,
    float* __restrict__ c_state,
    int* __restrict__ syncc,
    const float* __restrict__ w_ih_f, const float* __restrict__ w_hh_f, const float* __restrict__ b_f,
    const float* __restrict__ w_ih_b, const float* __restrict__ w_hh_b, const float* __restrict__ b_b)
{
    const int blk  = blockIdx.x;
    const int d    = blk >> 8;           // direction
    const int bid  = blk & 255;
    const int tid  = threadIdx.x;
    const int bb   = tid & 31;           // batch elem
    const int gl   = tid >> 5;           // 0..7 local gate
    const int ul_t = gl & 1;             // which of the 2 units
    const int gt   = gl >> 1;            // gate type: 0 i, 1 f, 2 g, 3 o
    const int unit = bid * 2 + ul_t;
    const int gidx = gt * cH + unit;     // row in [4H, *] weight matrices

    const float* __restrict__ wih = d ? w_ih_b : w_ih_f;
    const float* __restrict__ whh = d ? w_hh_b : w_hh_f;
    const float* __restrict__ bv  = d ? b_b    : b_f;

    const float4* __restrict__ wi4 = (const float4*)(wih + (size_t)gidx * cE);
    const float4* __restrict__ wh4 = (const float4*)(whh + (size_t)gidx * cH);
    const float bsum = bv[gidx];

    int* ctr = syncc + d * cS;
    __shared__ float gex[8][33];         // gate pre-activations, padded

    for (int s = 0; s < cS; ++s) {
        const int t  = d ? (cS - 1 - s) : s;   // time index this step
        const int tp = d ? (t + 1) : (t - 1);  // previous-h row

        float a0 = 0.f, a1 = 0.f, a2 = 0.f, a3 = 0.f;

        // x . w_ih  (256-dot, done exactly once per (t,gate,b))
        {
            const float4* __restrict__ xp = (const float4*)(x + ((size_t)t * cB + bb) * cE);
            #pragma unroll 8
            for (int e = 0; e < 64; e += 4) {
                float4 u0 = xp[e + 0], w0 = wi4[e + 0];
                float4 u1 = xp[e + 1], w1 = wi4[e + 1];
                float4 u2 = xp[e + 2], w2 = wi4[e + 2];
                float4 u3 = xp[e + 3], w3 = wi4[e + 3];
                a0 += u0.x * w0.x + u0.y * w0.y + u0.z * w0.z + u0.w * w0.w;
                a1 += u1.x * w1.x + u1.y * w1.y + u1.z * w1.z + u1.w * w1.w;
                a2 += u2.x * w2.x + u2.y * w2.y + u2.z * w2.z + u2.w * w2.w;
                a3 += u3.x * w3.x + u3.y * w3.y + u3.z * w3.z + u3.w * w3.w;
            }
        }
        // h_prev . w_hh  (512-dot), h_prev == 0 at first step
        if (s > 0) {
            const float4* __restrict__ hp =
                (const float4*)(h_all + ((size_t)tp * cB + bb) * (2 * cH) + (size_t)d * cH);
            #pragma unroll 8
            for (int j = 0; j < 128; j += 4) {
                float4 u0 = hp[j + 0], w0 = wh4[j + 0];
                float4 u1 = hp[j + 1], w1 = wh4[j + 1];
                float4 u2 = hp[j + 2], w2 = wh4[j + 2];
                float4 u3 = hp[j + 3], w3 = wh4[j + 3];
                a0 += u0.x * w0.x + u0.y * w0.y + u0.z * w0.z + u0.w * w0.w;
                a1 += u1.x * w1.x + u1.y * w1.y + u1.z * w1.z + u1.w * w1.w;
                a2 += u2.x * w2.x + u2.y * w2.y + u2.z * w2.z + u2.w * w2.w;
                a3 += u3.x * w3.x + u3.y * w3.y + u3.z * w3.z + u3.w * w3.w;
            }
        }
        const float acc = bsum + (a0 + a1) + (a2 + a3);

        gex[gl][bb] = acc;
        __syncthreads();

        if (tid < 64) {
            const int b2 = tid & 31;
            const int ul = tid >> 5;
            const int u  = bid * 2 + ul;
            const float gi = gex[0 + ul][b2];
            const float gf = gex[2 + ul][b2];
            const float gg = gex[4 + ul][b2];
            const float go = gex[6 + ul][b2];
            float* cp = c_state + ((size_t)d * cB + b2) * cH + u;
            const float cn = sigf(gf) * cp[0] + sigf(gi) * tanhf(gg);
            cp[0] = cn;
            h_all[((size_t)t * cB + b2) * (2 * cH) + (size_t)d * cH + u] = sigf(go) * tanhf(cn);
        }
        __syncthreads();

        // release h writes to the whole device, then per-direction barrier
        __threadfence();
        if (tid == 0) {
            __hip_atomic_fetch_add(ctr + s, 1, __ATOMIC_RELEASE, __HIP_MEMORY_SCOPE_AGENT);
            while (__hip_atomic_load(ctr + s, __ATOMIC_ACQUIRE, __HIP_MEMORY_SCOPE_AGENT) < 256) {
                __builtin_amdgcn_s_sleep(2);
            }
        }
        __syncthreads();
    }
}

// ---------------------------------------------------------------------------
// K3: feats[s][b][t] = h_all[s][b][:1024] . w_out[t][:] + b_out[t]
// one block per s, 320 threads = (b,t) pairs
// ---------------------------------------------------------------------------
__global__ void k_feats(const float* __restrict__ h_all,
                        const float* __restrict__ w_out,
                        const float* __restrict__ b_out,
                        float* __restrict__ feats)
{
    const int s   = blockIdx.x;
    const int tid = threadIdx.x;
    if (tid >= cB * cT) return;
    const int b   = tid / cT;
    const int t10 = tid - b * cT;
    const float4* hp = (const float4*)(h_all + ((size_t)s * cB + b) * (2 * cH));
    const float4* wp = (const float4*)(w_out + (size_t)t10 * (2 * cH));
    float a0 = 0.f, a1 = 0.f, a2 = 0.f, a3 = 0.f;
    #pragma unroll 4
    for (int j = 0; j < 256; j += 4) {
        float4 u0 = hp[j + 0], w0 = wp[j + 0];
        float4 u1 = hp[j + 1], w1 = wp[j + 1];
        float4 u2 = hp[j + 2], w2 = wp[j + 2];
        float4 u3 = hp[j + 3], w3 = wp[j + 3];
        a0 += u0.x * w0.x + u0.y * w0.y + u0.z * w0.z + u0.w * w0.w;
        a1 += u1.x * w1.x + u1.y * w1.y + u1.z * w1.z + u1.w * w1.w;
        a2 += u2.x * w2.x + u2.y * w2.y + u2.z * w2.z + u2.w * w2.w;
        a3 += u3.x * w3.x + u3.y * w3.y + u3.z * w3.z + u3.w * w3.w;
    }
    feats[((size_t)s * cB + b) * cT + t10] = b_out[t10] + (a0 + a1) + (a2 + a3);
}

// ---------------------------------------------------------------------------
// K4: CRF forward. Single block, thread = (b, next_tag). 256 masked steps.
// ---------------------------------------------------------------------------
__global__ void k_crf(const float* __restrict__ feats,
                      const int* __restrict__ lengths,
                      const float* __restrict__ trans,
                      float* __restrict__ out)
{
    __shared__ float fv[cB][12];
    __shared__ float term[cB][12];
    const int tid = threadIdx.x;
    const bool act = tid < cB * cT;
    const int b  = act ? tid / cT : 0;
    const int nx = act ? tid - b * cT : 0;
    float tr[cT];
    int len = 1;
    if (act) {
        len = lengths[b];
        #pragma unroll
        for (int p = 0; p < cT; ++p) tr[p] = trans[nx * cT + p];  // trans[next][prev]
        fv[b][nx] = (nx == 8) ? 0.0f : cNEG;                      // START=8
    }
    __syncthreads();

    for (int s = 0; s < cS; ++s) {
        float nv = 0.f;
        if (act) {
            float m = -1e30f;
            float cand[cT];
            #pragma unroll
            for (int p = 0; p < cT; ++p) {
                cand[p] = fv[b][p] + tr[p];
                m = fmaxf(m, cand[p]);
            }
            float sum = 0.f;
            #pragma unroll
            for (int p = 0; p < cT; ++p) sum += expf(cand[p] - m);
            nv = m + logf(sum) + feats[((size_t)s * cB + b) * cT + nx];
        }
        __syncthreads();
        if (act && s < len) fv[b][nx] = nv;
        __syncthreads();
    }

    if (act) term[b][nx] = fv[b][nx] + trans[9 * cT + nx];  // STOP=9 row
    __syncthreads();
    if (act && nx == 0) {
        float m = -1e30f;
        #pragma unroll
        for (int p = 0; p < cT; ++p) m = fmaxf(m, term[b][p]);
        float sum = 0.f;
        #pragma unroll
        for (int p = 0; p < cT; ++p) sum += expf(term[b][p] - m);
        out[b] = (m + logf(sum)) / (float)len;
    }
}

// ---------------------------------------------------------------------------
extern "C" void kernel_launch(void* const* d_in, const int* in_sizes, int n_in,
                              void* d_out, int out_size, void* d_ws, size_t ws_size,
                              hipStream_t stream)
{
    const int*   tokens = (const int*)d_in[0];
    const int*   lengths = (const int*)d_in[1];
    const float* emb    = (const float*)d_in[2];
    const float* w_ih_f = (const float*)d_in[3];
    const float* w_hh_f = (const float*)d_in[4];
    const float* b_f    = (const float*)d_in[5];
    const float* w_ih_b = (const float*)d_in[6];
    const float* w_hh_b = (const float*)d_in[7];
    const float* b_b    = (const float*)d_in[8];
    const float* w_out  = (const float*)d_in[9];
    const float* b_out  = (const float*)d_in[10];
    const float* trans  = (const float*)d_in[11];
    float* out = (float*)d_out;

    float* ws    = (float*)d_ws;
    float* x     = ws + X_OFF;
    float* h_all = ws + HALL_OFF;
    float* c_st  = ws + C_OFF;
    int*   syncc = (int*)(ws + SYNC_OFF);
    float* feats = ws + FEATS_OFF;

    // c_state + sync counters must be zero every call (ws is poisoned 0xAA)
    hipMemsetAsync(c_st, 0, ((size_t)2 * cB * cH + 512) * sizeof(float), stream);

    k_gather<<<1024, 512, 0, stream>>>(tokens, emb, x);
    k_recur<<<512, 256, 0, stream>>>(x, h_all, c_st, syncc,
                                     w_ih_f, w_hh_f, b_f,
                                     w_ih_b, w_hh_b, b_b);
    k_feats<<<cS, 320, 0, stream>>>(h_all, w_out, b_out, feats);
    k_crf<<<1, 320, 0, stream>>>(feats, lengths, trans, out);
}

// Round 5
// 6779.060 us; speedup vs baseline: 4.8070x; 4.8070x over previous
//
#include <hip/hip_runtime.h>
#include <cmath>

// Problem constants
constexpr int cS = 256;   // sequence length
constexpr int cB = 32;    // batch
constexpr int cE = 256;   // embedding dim
constexpr int cH = 512;   // hidden
constexpr int cT = 10;    // tags
constexpr float cNEG = -10000.0f;

// ws layout in floats:
//  h_all  [S][B][2H]       = 8,388,608  (cols 0:512 fwd, 512:1024 bwd)
//  sync   [2][4][S] (int)  = 2,048      (zeroed each launch)
//  feats  [S][B][T]        = 81,920
constexpr size_t HALL_OFF  = 0;
constexpr size_t SYNC_OFF  = HALL_OFF + (size_t)cS * cB * 2 * cH;
constexpr size_t FEATS_OFF = SYNC_OFF + 2048;

// Dynamic-LDS float offsets for k_recur3 (148,224 bytes -> 1 block/CU)
//  WU [16][772] : row r=g*4+ul, cols [0:256)=W_ih row, [256:768)=W_hh row
//  OP [32][772] : row b, cols [0:256)=x, [256:768)=h  (h-region doubles as
//                 the 16384-partial reduction buffer between compute+finalize)
constexpr int L_WU  = 0;
constexpr int L_OP  = 12352;
constexpr int L_TOT = 37056;     // floats
constexpr int RSTR  = 193;       // row stride in float4 (772 floats)

__device__ __forceinline__ float sigf(float v) { return 1.0f / (1.0f + expf(-v)); }
__device__ __forceinline__ float dot4(float4 a, float4 b) {
    return fmaf(a.x, b.x, fmaf(a.y, b.y, fmaf(a.z, b.z, a.w * b.w)));
}

// ---------------------------------------------------------------------------
// K2: persistent bidirectional LSTM, gather + x.W_ih fused, weights in LDS.
// 256 blocks (1/CU): blk>>7 = dir, (blk&127)*4 = first unit U0 (4 units).
// Compute: thread = (tau=tid>>5 -> rg=tau>>2, bg=tau&3; ksl=tid&31):
//   8 gate-rows x 8 batches x K-slice {ksl+32j}*4floats (24 of 768) -> 64 accs,
//   16 FMA per f4-read. Partials reduced via LDS overlay on OP h-region.
// Finalize: tid<128 = (ul=tid>>5, b=tid&31) owns one (unit,batch): sums 32
//   partials x 4 gates, activations, c in registers, h -> global.
// Sync: round-3-verified protocol. Plain h stores -> __syncthreads (vmcnt
//   drain) -> tid0 RELEASE fetch_add (L2 writeback) on 1 of 4 per-(d,s)
//   counters -> ACQUIRE poll of all 4 (cache inv) -> stage h from MALL.
// ---------------------------------------------------------------------------
__global__ __launch_bounds__(256, 1) void k_recur3(
    const int* __restrict__ tokens,
    const float* __restrict__ emb,
    float* __restrict__ h_all,
    int* __restrict__ syncc,
    const float* __restrict__ w_ih_f, const float* __restrict__ w_hh_f, const float* __restrict__ b_f,
    const float* __restrict__ w_ih_b, const float* __restrict__ w_hh_b, const float* __restrict__ b_b)
{
    extern __shared__ float lds[];
    float4* WU4 = (float4*)(lds + L_WU);
    float4* OP4 = (float4*)(lds + L_OP);
    float*  OPf = lds + L_OP;

    const int d   = blockIdx.x >> 7;
    const int U0  = (blockIdx.x & 127) * 4;
    const int tid = threadIdx.x;

    const float* __restrict__ wih = d ? w_ih_b : w_ih_f;
    const float* __restrict__ whh = d ? w_hh_b : w_hh_f;
    const float* __restrict__ bv  = d ? b_b    : b_f;

    // ---- preload weights into LDS (once): 3072 f4 ----
    #pragma unroll
    for (int i = 0; i < 12; ++i) {
        const int fid = i * 256 + tid;          // 0..3071
        const int r   = fid / 192;
        const int c   = fid % 192;
        const int g   = r >> 2, ul = r & 3;
        float4 v;
        if (c < 64) v = ((const float4*)(wih + (size_t)(g * cH + U0 + ul) * cE))[c];
        else        v = ((const float4*)(whh + (size_t)(g * cH + U0 + ul) * cH))[c - 64];
        WU4[r * RSTR + c] = v;
    }
    // ---- zero OP h-region (h0 == 0): 4096 f4 ----
    #pragma unroll
    for (int i = 0; i < 16; ++i) {
        const int fid = i * 256 + tid;
        OP4[(fid >> 7) * RSTR + 64 + (fid & 127)] = make_float4(0.f, 0.f, 0.f, 0.f);
    }
    // ---- stage x(t0): 2048 f4 ----
    {
        const int t0 = d ? (cS - 1) : 0;
        #pragma unroll
        for (int i = 0; i < 8; ++i) {
            const int fid = i * 256 + tid;
            const int b = fid >> 6, c = fid & 63;
            const int tok = tokens[b * cS + t0];
            OP4[b * RSTR + c] = ((const float4*)(emb + (size_t)tok * cE))[c];
        }
    }

    // thread roles
    const int ksl = tid & 31;
    const int tau = tid >> 5;
    const int rg  = tau >> 2;          // 0..1
    const int bg  = tau & 3;           // 0..3
    const int ful = tid >> 5;          // finalize: unit-local 0..3 (tid<128)
    const int fb  = tid & 31;          // finalize: batch
    float c_reg = 0.f;
    float bias[4] = {0.f, 0.f, 0.f, 0.f};
    if (tid < 128) {
        #pragma unroll
        for (int g = 0; g < 4; ++g) bias[g] = bv[g * cH + U0 + ful];
    }

    int* arr = syncc + ((size_t)d * 4 + (blockIdx.x & 3)) * cS;   // arrival ctr
    int* cbase = syncc + (size_t)d * 4 * cS;                      // 4 ctrs, this dir

    const float4* wb = WU4 + (rg * 8) * RSTR + ksl;
    const float4* ob = OP4 + (bg * 8) * RSTR + ksl;

    __syncthreads();

    for (int s = 0; s < cS; ++s) {
        const int t = d ? (cS - 1 - s) : s;

        // ---- B: compute 64 accumulators over this thread's K-slice ----
        float acc[8][8];
        #pragma unroll
        for (int i = 0; i < 8; ++i)
            #pragma unroll
            for (int k = 0; k < 8; ++k) acc[i][k] = 0.f;

        for (int j = 0; j < 6; ++j) {
            const int o = 32 * j;
            float4 wv[8], ov[8];
            #pragma unroll
            for (int i = 0; i < 8; ++i) wv[i] = wb[i * RSTR + o];
            #pragma unroll
            for (int i = 0; i < 8; ++i) ov[i] = ob[i * RSTR + o];
            #pragma unroll
            for (int i = 0; i < 8; ++i)
                #pragma unroll
                for (int k = 0; k < 8; ++k)
                    acc[i][k] += dot4(wv[i], ov[k]);
        }
        __syncthreads();   // all threads done READING OP

        // ---- C: partials -> OP h-region overlay  [b][256 + r*32 + ksl] ----
        #pragma unroll
        for (int i = 0; i < 8; ++i) {
            const int r = rg * 8 + i;
            #pragma unroll
            for (int k = 0; k < 8; ++k) {
                const int b = bg * 8 + k;
                OPf[b * 772 + 256 + r * 32 + ksl] = acc[i][k];
            }
        }
        __syncthreads();   // partials visible

        // ---- D: finalize one (unit, batch) per thread (tid<128) ----
        if (tid < 128) {
            float gs[4];
            #pragma unroll
            for (int g = 0; g < 4; ++g) {
                const int r = g * 4 + ful;
                const float4* pp = (const float4*)(OPf + fb * 772 + 256 + r * 32);
                float acc0 = 0.f;
                #pragma unroll
                for (int q = 0; q < 8; ++q) {
                    const float4 v = pp[q];
                    acc0 += (v.x + v.y) + (v.z + v.w);
                }
                gs[g] = acc0 + bias[g];
            }
            const float gi = sigf(gs[0]), gf = sigf(gs[1]);
            const float gg = tanhf(gs[2]), go = sigf(gs[3]);
            c_reg = gf * c_reg + gi * gg;
            const float hv = go * tanhf(c_reg);
            h_all[((size_t)t * cB + fb) * (2 * cH) + (size_t)d * cH + U0 + ful] = hv;
        }
        __syncthreads();   // drains h stores (vmcnt) block-wide

        // ---- E: arrive; prefetch x(t+1) during wait; ACQUIRE poll ----
        if (tid == 0) {
            __hip_atomic_fetch_add(arr + s, 1, __ATOMIC_RELEASE, __HIP_MEMORY_SCOPE_AGENT);
        }
        if (tid >= 128 && s + 1 < cS) {
            const int tn = d ? (cS - 2 - s) : (s + 1);
            #pragma unroll
            for (int i = 0; i < 16; ++i) {
                const int fid = i * 128 + (tid - 128);
                const int b = fid >> 6, c = fid & 63;
                const int tok = tokens[b * cS + tn];
                OP4[b * RSTR + c] = ((const float4*)(emb + (size_t)tok * cE))[c];
            }
        }
        if (tid == 0) {
            int sum;
            do {
                const int c0 = __hip_atomic_load(cbase + 0 * cS + s, __ATOMIC_ACQUIRE, __HIP_MEMORY_SCOPE_AGENT);
                const int c1 = __hip_atomic_load(cbase + 1 * cS + s, __ATOMIC_ACQUIRE, __HIP_MEMORY_SCOPE_AGENT);
                const int c2 = __hip_atomic_load(cbase + 2 * cS + s, __ATOMIC_ACQUIRE, __HIP_MEMORY_SCOPE_AGENT);
                const int c3 = __hip_atomic_load(cbase + 3 * cS + s, __ATOMIC_ACQUIRE, __HIP_MEMORY_SCOPE_AGENT);
                sum = ((c0 + c1) + (c2 + c3));
                if (sum < 128) __builtin_amdgcn_s_sleep(1);
            } while (sum < 128);
        }
        __syncthreads();   // whole block released; caches inv'd before staging

        // ---- F: stage h(t) (all 128 same-dir blocks' fresh rows) ----
        if (s + 1 < cS) {
            const float* hsrc = h_all + ((size_t)t * cB) * (2 * cH) + (size_t)d * cH;
            #pragma unroll
            for (int i = 0; i < 16; ++i) {
                const int fid = i * 256 + tid;
                const int b = fid >> 7, c = fid & 127;
                OP4[b * RSTR + 64 + c] = ((const float4*)(hsrc + (size_t)b * (2 * cH)))[c];
            }
        }
        __syncthreads();   // OP consistent for next compute
    }
}

// ---------------------------------------------------------------------------
// K3: feats[s][b][t] = h_all[s][b][:1024] . w_out[t][:] + b_out[t]
// ---------------------------------------------------------------------------
__global__ void k_feats(const float* __restrict__ h_all,
                        const float* __restrict__ w_out,
                        const float* __restrict__ b_out,
                        float* __restrict__ feats)
{
    const int s   = blockIdx.x;
    const int tid = threadIdx.x;
    if (tid >= cB * cT) return;
    const int b   = tid / cT;
    const int t10 = tid - b * cT;
    const float4* hp = (const float4*)(h_all + ((size_t)s * cB + b) * (2 * cH));
    const float4* wp = (const float4*)(w_out + (size_t)t10 * (2 * cH));
    float a0 = 0.f, a1 = 0.f, a2 = 0.f, a3 = 0.f;
    #pragma unroll 4
    for (int j = 0; j < 256; j += 4) {
        a0 += dot4(hp[j + 0], wp[j + 0]);
        a1 += dot4(hp[j + 1], wp[j + 1]);
        a2 += dot4(hp[j + 2], wp[j + 2]);
        a3 += dot4(hp[j + 3], wp[j + 3]);
    }
    feats[((size_t)s * cB + b) * cT + t10] = b_out[t10] + (a0 + a1) + (a2 + a3);
}

// ---------------------------------------------------------------------------
// K4: CRF forward. Single block, thread = (b, next_tag). 256 masked steps.
// ---------------------------------------------------------------------------
__global__ void k_crf(const float* __restrict__ feats,
                      const int* __restrict__ lengths,
                      const float* __restrict__ trans,
                      float* __restrict__ out)
{
    __shared__ float fv[cB][12];
    __shared__ float term[cB][12];
    const int tid = threadIdx.x;
    const bool act = tid < cB * cT;
    const int b  = act ? tid / cT : 0;
    const int nx = act ? tid - b * cT : 0;
    float tr[cT];
    int len = 1;
    if (act) {
        len = lengths[b];
        #pragma unroll
        for (int p = 0; p < cT; ++p) tr[p] = trans[nx * cT + p];  // trans[next][prev]
        fv[b][nx] = (nx == 8) ? 0.0f : cNEG;                      // START=8
    }
    __syncthreads();

    for (int s = 0; s < cS; ++s) {
        float nv = 0.f;
        if (act) {
            float m = -1e30f;
            float cand[cT];
            #pragma unroll
            for (int p = 0; p < cT; ++p) {
                cand[p] = fv[b][p] + tr[p];
                m = fmaxf(m, cand[p]);
            }
            float sum = 0.f;
            #pragma unroll
            for (int p = 0; p < cT; ++p) sum += expf(cand[p] - m);
            nv = m + logf(sum) + feats[((size_t)s * cB + b) * cT + nx];
        }
        __syncthreads();
        if (act && s < len) fv[b][nx] = nv;
        __syncthreads();
    }

    if (act) term[b][nx] = fv[b][nx] + trans[9 * cT + nx];  // STOP=9 row
    __syncthreads();
    if (act && nx == 0) {
        float m = -1e30f;
        #pragma unroll
        for (int p = 0; p < cT; ++p) m = fmaxf(m, term[b][p]);
        float sum = 0.f;
        #pragma unroll
        for (int p = 0; p < cT; ++p) sum += expf(term[b][p] - m);
        out[b] = (m + logf(sum)) / (float)len;
    }
}

// ---------------------------------------------------------------------------
extern "C" void kernel_launch(void* const* d_in, const int* in_sizes, int n_in,
                              void* d_out, int out_size, void* d_ws, size_t ws_size,
                              hipStream_t stream)
{
    const int*   tokens  = (const int*)d_in[0];
    const int*   lengths = (const int*)d_in[1];
    const float* emb     = (const float*)d_in[2];
    const float* w_ih_f  = (const float*)d_in[3];
    const float* w_hh_f  = (const float*)d_in[4];
    const float* b_f     = (const float*)d_in[5];
    const float* w_ih_b  = (const float*)d_in[6];
    const float* w_hh_b  = (const float*)d_in[7];
    const float* b_b     = (const float*)d_in[8];
    const float* w_out   = (const float*)d_in[9];
    const float* b_out   = (const float*)d_in[10];
    const float* trans   = (const float*)d_in[11];
    float* out = (float*)d_out;

    float* ws    = (float*)d_ws;
    float* h_all = ws + HALL_OFF;
    int*   syncc = (int*)(ws + SYNC_OFF);
    float* feats = ws + FEATS_OFF;

    // sync counters must be zero every call (ws is poisoned 0xAA)
    hipMemsetAsync(syncc, 0, 2048 * sizeof(int), stream);

    // opt in to >64KB dynamic LDS (148 KB/block -> exactly 1 block/CU,
    // all 256 blocks co-resident: spin barrier cannot deadlock)
    static bool attr_set = false;
    if (!attr_set) {
        hipFuncSetAttribute((const void*)k_recur3,
                            hipFuncAttributeMaxDynamicSharedMemorySize,
                            L_TOT * (int)sizeof(float));
        attr_set = true;
    }

    k_recur3<<<256, 256, L_TOT * sizeof(float), stream>>>(
        tokens, emb, h_all, syncc,
        w_ih_f, w_hh_f, b_f, w_ih_b, w_hh_b, b_b);
    k_feats<<<cS, 320, 0, stream>>>(h_all, w_out, b_out, feats);
    k_crf<<<1, 320, 0, stream>>>(feats, lengths, trans, out);
}

// Round 7
// 3867.381 us; speedup vs baseline: 8.4260x; 1.7529x over previous
//
#include <hip/hip_runtime.h>
#include <cmath>

// Problem constants
constexpr int cS = 256;   // sequence length
constexpr int cB = 32;    // batch
constexpr int cE = 256;   // embedding dim
constexpr int cH = 512;   // hidden
constexpr int cT = 10;    // tags
constexpr float cNEG = -10000.0f;

// ws layout in floats:
//  h_all  [S][B][2H]       = 8,388,608  (cols 0:512 fwd, 512:1024 bwd)
//  sync   [2][S][4] (int)  = 2,048      (zeroed each launch)
//  feats  [S][B][T]        = 81,920
constexpr size_t HALL_OFF  = 0;
constexpr size_t SYNC_OFF  = HALL_OFF + (size_t)cS * cB * 2 * cH;
constexpr size_t FEATS_OFF = SYNC_OFF + 2048;

// Dynamic-LDS float offsets for k_recur4 (148,224 bytes -> 1 block/CU)
//  WU [16][772] : row r=g*4+ul, cols [0:256)=W_ih row, [256:768)=W_hh row
//  OP [32][772] : row b, cols [0:256)=x, [256:768)=h  (h-region doubles as
//                 the 16384-partial reduction buffer between compute+finalize)
constexpr int L_WU  = 0;
constexpr int L_OP  = 12352;
constexpr int L_TOT = 37056;     // floats
constexpr int RSTR  = 193;       // row stride in float4 (772 floats)

__device__ __forceinline__ float sigf(float v) { return 1.0f / (1.0f + expf(-v)); }
__device__ __forceinline__ float dot4(float4 a, float4 b) {
    return fmaf(a.x, b.x, fmaf(a.y, b.y, fmaf(a.z, b.z, a.w * b.w)));
}

// ---------------------------------------------------------------------------
// K2: persistent bidirectional LSTM, gather + x.W_ih fused, weights in LDS.
// 256 blocks (1/CU): blk>>7 = dir, (blk&127)*4 = first unit U0 (4 units).
// Compute: thread = (tau=tid>>5 -> rg=tau>>2, bg=tau&3; ksl=tid&31):
//   8 gate-rows x 8 batches, K-slice cols {ksl+32j}(f4) of [x(64f4)|h(128f4)].
//   j=0,1 = x-part (step-invariant inputs, computed PRE-barrier for t+1);
//   j=2..5 = h-part (post-barrier). 16 FMA per f4-read, 64 accs in registers
//   carried across the barrier.
// Sync per step: h stores -> __syncthreads (vmcnt drain) -> tid0 RELEASE
//   fetch_add on 1 of 4 contiguous per-(d,s) counters -> [stage x(t+1) +
//   x-dot in the wait window] -> tid0 RELAXED poll (int-wise, MALL-direct,
//   NO invalidation) -> single ACQUIRE load (one cache-inv per step) ->
//   __syncthreads -> stage h from MALL.
// ---------------------------------------------------------------------------
__global__ __launch_bounds__(256, 1) void k_recur4(
    const int* __restrict__ tokens,
    const float* __restrict__ emb,
    float* __restrict__ h_all,
    int* __restrict__ syncc,
    const float* __restrict__ w_ih_f, const float* __restrict__ w_hh_f, const float* __restrict__ b_f,
    const float* __restrict__ w_ih_b, const float* __restrict__ w_hh_b, const float* __restrict__ b_b)
{
    extern __shared__ float lds[];
    float4* WU4 = (float4*)(lds + L_WU);
    float4* OP4 = (float4*)(lds + L_OP);
    float*  OPf = lds + L_OP;

    const int d   = blockIdx.x >> 7;
    const int U0  = (blockIdx.x & 127) * 4;
    const int tid = threadIdx.x;

    const float* __restrict__ wih = d ? w_ih_b : w_ih_f;
    const float* __restrict__ whh = d ? w_hh_b : w_hh_f;
    const float* __restrict__ bv  = d ? b_b    : b_f;

    // ---- preload weights into LDS (once): 3072 f4 ----
    #pragma unroll
    for (int i = 0; i < 12; ++i) {
        const int fid = i * 256 + tid;          // 0..3071
        const int r   = fid / 192;
        const int c   = fid % 192;
        const int g   = r >> 2, ul = r & 3;
        float4 v;
        if (c < 64) v = ((const float4*)(wih + (size_t)(g * cH + U0 + ul) * cE))[c];
        else        v = ((const float4*)(whh + (size_t)(g * cH + U0 + ul) * cH))[c - 64];
        WU4[r * RSTR + c] = v;
    }
    // ---- zero OP h-region (h0 == 0): 4096 f4 ----
    #pragma unroll
    for (int i = 0; i < 16; ++i) {
        const int fid = i * 256 + tid;
        OP4[(fid >> 7) * RSTR + 64 + (fid & 127)] = make_float4(0.f, 0.f, 0.f, 0.f);
    }
    // ---- stage x(t0): 2048 f4 ----
    {
        const int t0 = d ? (cS - 1) : 0;
        #pragma unroll
        for (int i = 0; i < 8; ++i) {
            const int fid = i * 256 + tid;
            const int b = fid >> 6, c = fid & 63;
            const int tok = tokens[b * cS + t0];
            OP4[b * RSTR + c] = ((const float4*)(emb + (size_t)tok * cE))[c];
        }
    }

    // thread roles
    const int ksl = tid & 31;
    const int tau = tid >> 5;
    const int rg  = tau >> 2;          // 0..1
    const int bg  = tau & 3;           // 0..3
    const int ful = tid >> 5;          // finalize: unit-local 0..3 (tid<128)
    const int fb  = tid & 31;          // finalize: batch
    float c_reg = 0.f;
    float bias[4] = {0.f, 0.f, 0.f, 0.f};
    if (tid < 128) {
        #pragma unroll
        for (int g = 0; g < 4; ++g) bias[g] = bv[g * cH + U0 + ful];
    }

    int* cb_d = syncc + (size_t)d * cS * 4;       // this dir's counters [s][4]
    const int aidx = blockIdx.x & 3;              // which of the 4 to bump

    const float4* wb = WU4 + (rg * 8) * RSTR + ksl;
    const float4* ob = OP4 + (bg * 8) * RSTR + ksl;

    float acc[8][8];
    __syncthreads();

    // ---- prologue: x-part (j=0,1) for t0 ----
    #pragma unroll
    for (int i = 0; i < 8; ++i)
        #pragma unroll
        for (int k = 0; k < 8; ++k) acc[i][k] = 0.f;
    #pragma unroll
    for (int j = 0; j < 2; ++j) {
        const int o = 32 * j;
        float4 wv[8], ov[8];
        #pragma unroll
        for (int i = 0; i < 8; ++i) wv[i] = wb[i * RSTR + o];
        #pragma unroll
        for (int i = 0; i < 8; ++i) ov[i] = ob[i * RSTR + o];
        #pragma unroll
        for (int i = 0; i < 8; ++i)
            #pragma unroll
            for (int k = 0; k < 8; ++k)
                acc[i][k] += dot4(wv[i], ov[k]);
    }

    for (int s = 0; s < cS; ++s) {
        const int t  = d ? (cS - 1 - s) : s;
        const int tp = d ? (t + 1) : (t - 1);

        // ---- A: stage h(t_prev) (post-ACQUIRE of previous step) ----
        if (s > 0) {
            const float* hsrc = h_all + ((size_t)tp * cB) * (2 * cH) + (size_t)d * cH;
            #pragma unroll
            for (int i = 0; i < 16; ++i) {
                const int fid = i * 256 + tid;
                const int b = fid >> 7, c = fid & 127;
                OP4[b * RSTR + 64 + c] = ((const float4*)(hsrc + (size_t)b * (2 * cH)))[c];
            }
        }
        __syncthreads();   // #1: h staged (acc already holds x-part)

        // ---- B: h-part (j=2..5) into carried acc ----
        if (s > 0) {
            for (int j = 2; j < 6; ++j) {
                const int o = 32 * j;
                float4 wv[8], ov[8];
                #pragma unroll
                for (int i = 0; i < 8; ++i) wv[i] = wb[i * RSTR + o];
                #pragma unroll
                for (int i = 0; i < 8; ++i) ov[i] = ob[i * RSTR + o];
                #pragma unroll
                for (int i = 0; i < 8; ++i)
                    #pragma unroll
                    for (int k = 0; k < 8; ++k)
                        acc[i][k] += dot4(wv[i], ov[k]);
            }
        }
        __syncthreads();   // #2: all reads of OP done

        // ---- C: partials -> OP h-region overlay  [b][256 + r*32 + ksl] ----
        #pragma unroll
        for (int i = 0; i < 8; ++i) {
            const int r = rg * 8 + i;
            #pragma unroll
            for (int k = 0; k < 8; ++k) {
                const int b = bg * 8 + k;
                OPf[b * 772 + 256 + r * 32 + ksl] = acc[i][k];
            }
        }
        __syncthreads();   // #3: partials visible

        // ---- D: finalize one (unit, batch) per thread (tid<128) ----
        if (tid < 128) {
            float gs[4];
            #pragma unroll
            for (int g = 0; g < 4; ++g) {
                const int r = g * 4 + ful;
                const float4* pp = (const float4*)(OPf + fb * 772 + 256 + r * 32);
                float acc0 = 0.f;
                #pragma unroll
                for (int q = 0; q < 8; ++q) {
                    const float4 v = pp[q];
                    acc0 += (v.x + v.y) + (v.z + v.w);
                }
                gs[g] = acc0 + bias[g];
            }
            const float gi = sigf(gs[0]), gf = sigf(gs[1]);
            const float gg = tanhf(gs[2]), go = sigf(gs[3]);
            c_reg = gf * c_reg + gi * gg;
            const float hv = go * tanhf(c_reg);
            h_all[((size_t)t * cB + fb) * (2 * cH) + (size_t)d * cH + U0 + ful] = hv;
        }
        __syncthreads();   // #4: drains h stores (vmcnt) block-wide

        if (s + 1 < cS) {
            // ---- E: arrive, then hide x(t+1) staging + x-dot in the wait ----
            if (tid == 0) {
                __hip_atomic_fetch_add(cb_d + s * 4 + aidx, 1,
                                       __ATOMIC_RELEASE, __HIP_MEMORY_SCOPE_AGENT);
            }
            const int tn = d ? (cS - 2 - s) : (s + 1);
            if (tid >= 128) {
                #pragma unroll
                for (int i = 0; i < 16; ++i) {
                    const int fid = i * 128 + (tid - 128);
                    const int b = fid >> 6, c = fid & 63;
                    const int tok = tokens[b * cS + tn];
                    OP4[b * RSTR + c] = ((const float4*)(emb + (size_t)tok * cE))[c];
                }
            }
            __syncthreads();   // #5: x(t+1) staged

            // x-part (j=0,1) for t+1 into fresh acc (pre-barrier work)
            #pragma unroll
            for (int i = 0; i < 8; ++i)
                #pragma unroll
                for (int k = 0; k < 8; ++k) acc[i][k] = 0.f;
            #pragma unroll
            for (int j = 0; j < 2; ++j) {
                const int o = 32 * j;
                float4 wv[8], ov[8];
                #pragma unroll
                for (int i = 0; i < 8; ++i) wv[i] = wb[i * RSTR + o];
                #pragma unroll
                for (int i = 0; i < 8; ++i) ov[i] = ob[i * RSTR + o];
                #pragma unroll
                for (int i = 0; i < 8; ++i)
                    #pragma unroll
                    for (int k = 0; k < 8; ++k)
                        acc[i][k] += dot4(wv[i], ov[k]);
            }

            if (tid == 0) {
                // RELAXED poll: MALL-direct loads, pipelined, NO cache inv
                int* cb = cb_d + s * 4;
                int sum;
                do {
                    const int c0 = __hip_atomic_load(cb + 0, __ATOMIC_RELAXED, __HIP_MEMORY_SCOPE_AGENT);
                    const int c1 = __hip_atomic_load(cb + 1, __ATOMIC_RELAXED, __HIP_MEMORY_SCOPE_AGENT);
                    const int c2 = __hip_atomic_load(cb + 2, __ATOMIC_RELAXED, __HIP_MEMORY_SCOPE_AGENT);
                    const int c3 = __hip_atomic_load(cb + 3, __ATOMIC_RELAXED, __HIP_MEMORY_SCOPE_AGENT);
                    sum = ((c0 + c1) + (c2 + c3));
                    if (sum < 128) __builtin_amdgcn_s_sleep(2);
                } while (sum < 128);
                // single ACQUIRE: one cache-inv per step, orders the h reads
                (void)__hip_atomic_load(cb + 0, __ATOMIC_ACQUIRE, __HIP_MEMORY_SCOPE_AGENT);
            }
            __syncthreads();   // #6: released; caches inv'd before staging h
        }
    }
}

// ---------------------------------------------------------------------------
// K3: feats[s][b][t] = h_all[s][b][:1024] . w_out[t][:] + b_out[t]
// ---------------------------------------------------------------------------
__global__ void k_feats(const float* __restrict__ h_all,
                        const float* __restrict__ w_out,
                        const float* __restrict__ b_out,
                        float* __restrict__ feats)
{
    const int s   = blockIdx.x;
    const int tid = threadIdx.x;
    if (tid >= cB * cT) return;
    const int b   = tid / cT;
    const int t10 = tid - b * cT;
    const float4* hp = (const float4*)(h_all + ((size_t)s * cB + b) * (2 * cH));
    const float4* wp = (const float4*)(w_out + (size_t)t10 * (2 * cH));
    float a0 = 0.f, a1 = 0.f, a2 = 0.f, a3 = 0.f;
    #pragma unroll 4
    for (int j = 0; j < 256; j += 4) {
        a0 += dot4(hp[j + 0], wp[j + 0]);
        a1 += dot4(hp[j + 1], wp[j + 1]);
        a2 += dot4(hp[j + 2], wp[j + 2]);
        a3 += dot4(hp[j + 3], wp[j + 3]);
    }
    feats[((size_t)s * cB + b) * cT + t10] = b_out[t10] + (a0 + a1) + (a2 + a3);
}

// ---------------------------------------------------------------------------
// K4: CRF forward. Single block, thread = (b, next_tag). 256 masked steps.
// ---------------------------------------------------------------------------
__global__ void k_crf(const float* __restrict__ feats,
                      const int* __restrict__ lengths,
                      const float* __restrict__ trans,
                      float* __restrict__ out)
{
    __shared__ float fv[cB][12];
    __shared__ float term[cB][12];
    const int tid = threadIdx.x;
    const bool act = tid < cB * cT;
    const int b  = act ? tid / cT : 0;
    const int nx = act ? tid - b * cT : 0;
    float tr[cT];
    int len = 1;
    if (act) {
        len = lengths[b];
        #pragma unroll
        for (int p = 0; p < cT; ++p) tr[p] = trans[nx * cT + p];  // trans[next][prev]
        fv[b][nx] = (nx == 8) ? 0.0f : cNEG;                      // START=8
    }
    __syncthreads();

    for (int s = 0; s < cS; ++s) {
        float nv = 0.f;
        if (act) {
            float m = -1e30f;
            float cand[cT];
            #pragma unroll
            for (int p = 0; p < cT; ++p) {
                cand[p] = fv[b][p] + tr[p];
                m = fmaxf(m, cand[p]);
            }
            float sum = 0.f;
            #pragma unroll
            for (int p = 0; p < cT; ++p) sum += expf(cand[p] - m);
            nv = m + logf(sum) + feats[((size_t)s * cB + b) * cT + nx];
        }
        __syncthreads();
        if (act && s < len) fv[b][nx] = nv;
        __syncthreads();
    }

    if (act) term[b][nx] = fv[b][nx] + trans[9 * cT + nx];  // STOP=9 row
    __syncthreads();
    if (act && nx == 0) {
        float m = -1e30f;
        #pragma unroll
        for (int p = 0; p < cT; ++p) m = fmaxf(m, term[b][p]);
        float sum = 0.f;
        #pragma unroll
        for (int p = 0; p < cT; ++p) sum += expf(term[b][p] - m);
        out[b] = (m + logf(sum)) / (float)len;
    }
}

// ---------------------------------------------------------------------------
extern "C" void kernel_launch(void* const* d_in, const int* in_sizes, int n_in,
                              void* d_out, int out_size, void* d_ws, size_t ws_size,
                              hipStream_t stream)
{
    const int*   tokens  = (const int*)d_in[0];
    const int*   lengths = (const int*)d_in[1];
    const float* emb     = (const float*)d_in[2];
    const float* w_ih_f  = (const float*)d_in[3];
    const float* w_hh_f  = (const float*)d_in[4];
    const float* b_f     = (const float*)d_in[5];
    const float* w_ih_b  = (const float*)d_in[6];
    const float* w_hh_b  = (const float*)d_in[7];
    const float* b_b     = (const float*)d_in[8];
    const float* w_out   = (const float*)d_in[9];
    const float* b_out   = (const float*)d_in[10];
    const float* trans   = (const float*)d_in[11];
    float* out = (float*)d_out;

    float* ws    = (float*)d_ws;
    float* h_all = ws + HALL_OFF;
    int*   syncc = (int*)(ws + SYNC_OFF);
    float* feats = ws + FEATS_OFF;

    // sync counters must be zero every call (ws is poisoned 0xAA)
    hipMemsetAsync(syncc, 0, 2048 * sizeof(int), stream);

    // opt in to >64KB dynamic LDS (148 KB/block -> exactly 1 block/CU,
    // all 256 blocks co-resident: spin barrier cannot deadlock)
    static bool attr_set = false;
    if (!attr_set) {
        hipFuncSetAttribute((const void*)k_recur4,
                            hipFuncAttributeMaxDynamicSharedMemorySize,
                            L_TOT * (int)sizeof(float));
        attr_set = true;
    }

    k_recur4<<<256, 256, L_TOT * sizeof(float), stream>>>(
        tokens, emb, h_all, syncc,
        w_ih_f, w_hh_f, b_f, w_ih_b, w_hh_b, b_b);
    k_feats<<<cS, 320, 0, stream>>>(h_all, w_out, b_out, feats);
    k_crf<<<1, 320, 0, stream>>>(feats, lengths, trans, out);
}